// Round 3
// baseline (319.728 us; speedup 1.0000x reference)
//
#include <hip/hip_runtime.h>
#include <hip/hip_bf16.h>
#include <stdint.h>

#define S_LEN 2048
#define DM    1024
#define NH    16
#define DK    64
#define NBATCH 2

typedef __attribute__((ext_vector_type(8))) short bf8_t;   // 8 bf16 (4 VGPRs)
typedef __attribute__((ext_vector_type(4))) float f4_t;    // MFMA accum

using bf16 = __hip_bfloat16;

#define NEG_BIG (-1.0e30f)

static __device__ __forceinline__ f4_t mfma16(bf8_t a, bf8_t b, f4_t c) {
    return __builtin_amdgcn_mfma_f32_16x16x32_bf16(a, b, c, 0, 0, 0);
}

static __device__ __forceinline__ short f2b(float f) {
    __hip_bfloat16 h = __float2bfloat16(f);
    return *reinterpret_cast<short*>(&h);
}

// ---------------------------------------------------------------------------
// GEMM: C[M,N] = A[M,K] * W[N,K]^T   (M=4096, N=1024, K=1024)
// MODE 0: A fp32 (x), W fp32, C bf16 scattered into head-major [B,H,S,DK]
// MODE 1: A bf16 (attn out ws), W fp32, C fp32 row-major (d_out)
// 128x128 tile, BK=32, 4 waves (2x2), each wave 64x64 = 4x4 16x16 frags.
// ---------------------------------------------------------------------------
template<int MODE>
__global__ __launch_bounds__(256)
void gemm_bt(const void* __restrict__ Av, const float* __restrict__ W,
             void* __restrict__ Cv) {
    constexpr int N = DM;
    constexpr int K = DM;
    constexpr int BM = 128, BK = 32, LDT = BK + 8; // +8 bf16 = 16B pad

    __shared__ bf16 As[BM][LDT];
    __shared__ bf16 Bs[BM][LDT];

    const int tid  = threadIdx.x;
    const int lane = tid & 63;
    const int w    = tid >> 6;
    const int wr   = w >> 1, wc = w & 1;
    const int lhi  = lane >> 4, llo = lane & 15;
    const int bm   = blockIdx.x * BM;
    const int bn   = blockIdx.y * BM;

    f4_t acc[4][4] = {};

    for (int k0 = 0; k0 < K; k0 += BK) {
        __syncthreads();
        // stage A,B tiles: 512 chunks of 8 elems each, 2 per thread per matrix
        #pragma unroll
        for (int t = 0; t < 2; ++t) {
            int c   = t * 256 + tid;          // 0..511
            int row = c >> 2;                 // 0..127
            int col = (c & 3) << 3;           // 0,8,16,24

            // A tile
            if (MODE == 0) {
                const float* s0 = (const float*)Av + (size_t)(bm + row) * K + k0 + col;
                float4 f0 = *(const float4*)(s0);
                float4 f1 = *(const float4*)(s0 + 4);
                bf8_t a8;
                a8[0]=f2b(f0.x); a8[1]=f2b(f0.y); a8[2]=f2b(f0.z); a8[3]=f2b(f0.w);
                a8[4]=f2b(f1.x); a8[5]=f2b(f1.y); a8[6]=f2b(f1.z); a8[7]=f2b(f1.w);
                *(bf8_t*)(&As[row][col]) = a8;
            } else {
                *(bf8_t*)(&As[row][col]) =
                    *(const bf8_t*)((const bf16*)Av + (size_t)(bm + row) * K + k0 + col);
            }
            // W tile (always fp32)
            {
                const float* s0 = W + (size_t)(bn + row) * K + k0 + col;
                float4 f0 = *(const float4*)(s0);
                float4 f1 = *(const float4*)(s0 + 4);
                bf8_t b8;
                b8[0]=f2b(f0.x); b8[1]=f2b(f0.y); b8[2]=f2b(f0.z); b8[3]=f2b(f0.w);
                b8[4]=f2b(f1.x); b8[5]=f2b(f1.y); b8[6]=f2b(f1.z); b8[7]=f2b(f1.w);
                *(bf8_t*)(&Bs[row][col]) = b8;
            }
        }
        __syncthreads();

        bf8_t af[4], bfr[4];
        #pragma unroll
        for (int i = 0; i < 4; ++i) {
            af[i]  = *(const bf8_t*)(&As[wr * 64 + i * 16 + llo][lhi * 8]);
            bfr[i] = *(const bf8_t*)(&Bs[wc * 64 + i * 16 + llo][lhi * 8]);
        }
        #pragma unroll
        for (int mi = 0; mi < 4; ++mi)
            #pragma unroll
            for (int ni = 0; ni < 4; ++ni)
                acc[mi][ni] = mfma16(af[mi], bfr[ni], acc[mi][ni]);
    }

    // epilogue: C/D layout col = lane&15, row = (lane>>4)*4 + r  [m89/m91]
    #pragma unroll
    for (int mi = 0; mi < 4; ++mi) {
        #pragma unroll
        for (int ni = 0; ni < 4; ++ni) {
            #pragma unroll
            for (int r = 0; r < 4; ++r) {
                int m = bm + wr * 64 + mi * 16 + lhi * 4 + r;
                int n = bn + wc * 64 + ni * 16 + llo;
                if (MODE == 0) {
                    int b = m >> 11, s = m & (S_LEN - 1);
                    int h = n >> 6,  d = n & (DK - 1);
                    ((bf16*)Cv)[(((size_t)(b * NH + h) * S_LEN) + s) * DK + d] =
                        __float2bfloat16(acc[mi][ni][r]);
                } else {
                    ((float*)Cv)[(size_t)m * N + n] = acc[mi][ni][r];
                }
            }
        }
    }
}

// ---------------------------------------------------------------------------
// Causal flash attention. Grid: (S/64 q-tiles, B*H). 256 thr = 4 waves.
// Wave w owns q-rows [q0+16w, q0+16w+16). KV tiles of 64, shared across waves.
// Q,K,V are head-major [B*H][S][DK] bf16. Output scattered to [B][S][H*DK].
// No +-inf anywhere: masks use -1e30 so every exp arg is finite.
// ---------------------------------------------------------------------------
__global__ __launch_bounds__(256)
void attn_fwd(const bf16* __restrict__ Q, const bf16* __restrict__ K,
              const bf16* __restrict__ V, bf16* __restrict__ AO) {
    const int qt = blockIdx.x;
    const int bh = blockIdx.y;
    const int q0 = qt * 64;

    const bf16* Qh = Q + (size_t)bh * S_LEN * DK;
    const bf16* Kh = K + (size_t)bh * S_LEN * DK;
    const bf16* Vh = V + (size_t)bh * S_LEN * DK;

    const int tid  = threadIdx.x;
    const int lane = tid & 63;
    const int w    = tid >> 6;
    const int lhi  = lane >> 4, llo = lane & 15;

    __shared__ bf16 Ks[64][72];      // K tile, row-major [kv][d], pad to 72
    __shared__ bf16 Vt[64][72];      // V tile transposed [d][kv]
    __shared__ bf16 Pl[4][16][72];   // per-wave P tile [q][kv]

    // Q A-frags: row = llo (q within wave tile), k-chunk = lhi*8 (+0/+32)
    const bf16* qrow = Qh + (size_t)(q0 + w * 16 + llo) * DK;
    const bf8_t qf0 = *(const bf8_t*)(qrow + lhi * 8);
    const bf8_t qf1 = *(const bf8_t*)(qrow + 32 + lhi * 8);

    f4_t o[4] = {};
    float mr[4], lr[4];
    #pragma unroll
    for (int r = 0; r < 4; ++r) { mr[r] = NEG_BIG; lr[r] = 0.f; }
    const float scale = 0.125f;   // 1/sqrt(64)

    for (int kv0 = 0; kv0 <= q0; kv0 += 64) {
        __syncthreads();
        // stage K (row-major) and V (transposed): 512 chunks of 8 bf16
        #pragma unroll
        for (int t = 0; t < 2; ++t) {
            int c   = t * 256 + tid;
            int row = c >> 3;             // kv within tile 0..63
            int col = (c & 7) << 3;       // d 0,8,..,56
            *(bf8_t*)&Ks[row][col] =
                *(const bf8_t*)(Kh + (size_t)(kv0 + row) * DK + col);
            bf8_t vv = *(const bf8_t*)(Vh + (size_t)(kv0 + row) * DK + col);
            #pragma unroll
            for (int j = 0; j < 8; ++j)
                *reinterpret_cast<short*>(&Vt[col + j][row]) = vv[j];
        }
        __syncthreads();

        // scores: s[nf] is 16q x 16kv frag; K B-frag from row-major Ks
        f4_t s[4] = {};
        #pragma unroll
        for (int nf = 0; nf < 4; ++nf) {
            bf8_t k0f = *(const bf8_t*)&Ks[nf * 16 + llo][lhi * 8];
            bf8_t k1f = *(const bf8_t*)&Ks[nf * 16 + llo][32 + lhi * 8];
            s[nf] = mfma16(qf0, k0f, s[nf]);
            s[nf] = mfma16(qf1, k1f, s[nf]);
        }

        const bool diag = (kv0 == q0);
        #pragma unroll
        for (int nf = 0; nf < 4; ++nf) {
            #pragma unroll
            for (int r = 0; r < 4; ++r) {
                float v = s[nf][r] * scale;
                if (diag && (nf * 16 + llo) > (w * 16 + lhi * 4 + r))
                    v = NEG_BIG;
                s[nf][r] = v;
            }
        }

        // per-row max over 64 kv cols: 4 frags then 16-lane butterfly
        float pm[4];
        #pragma unroll
        for (int r = 0; r < 4; ++r)
            pm[r] = fmaxf(fmaxf(s[0][r], s[1][r]), fmaxf(s[2][r], s[3][r]));
        #pragma unroll
        for (int off = 1; off < 16; off <<= 1) {
            #pragma unroll
            for (int r = 0; r < 4; ++r)
                pm[r] = fmaxf(pm[r], __shfl_xor(pm[r], off));
        }

        float alpha[4];
        #pragma unroll
        for (int r = 0; r < 4; ++r) {
            float mn = fmaxf(mr[r], pm[r]);
            alpha[r] = __expf(mr[r] - mn);   // finite - finite, exp<=1
            mr[r] = mn;
        }

        // P = exp(s - m), row-sum, stash P (bf16) to per-wave LDS
        float rs[4] = {0.f, 0.f, 0.f, 0.f};
        #pragma unroll
        for (int nf = 0; nf < 4; ++nf) {
            #pragma unroll
            for (int r = 0; r < 4; ++r) {
                float p = __expf(s[nf][r] - mr[r]);
                rs[r] += p;
                Pl[w][lhi * 4 + r][nf * 16 + llo] = __float2bfloat16(p);
            }
        }
        #pragma unroll
        for (int off = 1; off < 16; off <<= 1) {
            #pragma unroll
            for (int r = 0; r < 4; ++r)
                rs[r] += __shfl_xor(rs[r], off);
        }
        #pragma unroll
        for (int r = 0; r < 4; ++r) lr[r] = lr[r] * alpha[r] + rs[r];
        #pragma unroll
        for (int df = 0; df < 4; ++df)
            #pragma unroll
            for (int r = 0; r < 4; ++r) o[df][r] *= alpha[r];

        // bulletproof ordering of P writes vs PV reads (debug round):
        __syncthreads();

        // PV: A = P [q][kv] from Pl, B = V [kv][d] from transposed Vt
        #pragma unroll
        for (int df = 0; df < 4; ++df) {
            #pragma unroll
            for (int kk = 0; kk < 2; ++kk) {
                bf8_t pa = *(const bf8_t*)&Pl[w][llo][kk * 32 + lhi * 8];
                bf8_t vb = *(const bf8_t*)&Vt[df * 16 + llo][kk * 32 + lhi * 8];
                o[df] = mfma16(pa, vb, o[df]);
            }
        }
    }

    // epilogue: O /= l, scatter to [B][S][H*DK]
    const int b = bh >> 4, h = bh & (NH - 1);
    #pragma unroll
    for (int r = 0; r < 4; ++r) {
        float inv = 1.0f / lr[r];
        int q = q0 + w * 16 + lhi * 4 + r;
        bf16* orow = AO + ((size_t)(b * S_LEN + q) * DM) + h * DK;
        #pragma unroll
        for (int df = 0; df < 4; ++df)
            orow[df * 16 + llo] = __float2bfloat16(o[df][r] * inv);
    }
}

// ---------------------------------------------------------------------------
extern "C" void kernel_launch(void* const* d_in, const int* in_sizes, int n_in,
                              void* d_out, int out_size, void* d_ws, size_t ws_size,
                              hipStream_t stream) {
    const float* x  = (const float*)d_in[0];
    const float* wq = (const float*)d_in[1];
    const float* wk = (const float*)d_in[2];
    const float* wv = (const float*)d_in[3];
    const float* wo = (const float*)d_in[4];
    float* out = (float*)d_out;

    const size_t elems = (size_t)NBATCH * S_LEN * DM;  // 4,194,304
    if (ws_size < elems * 4 * sizeof(bf16)) return;    // need ~33.6 MB

    bf16* qws = (bf16*)d_ws;
    bf16* kws = qws + elems;
    bf16* vws = kws + elems;
    bf16* aws = vws + elems;

    dim3 blk(256);
    dim3 gg(32, 8);          // (4096/128, 1024/128)
    gemm_bt<0><<<gg, blk, 0, stream>>>(x, wq, qws);
    gemm_bt<0><<<gg, blk, 0, stream>>>(x, wk, kws);
    gemm_bt<0><<<gg, blk, 0, stream>>>(x, wv, vws);
    attn_fwd<<<dim3(S_LEN / 64, NBATCH * NH), blk, 0, stream>>>(qws, kws, vws, aws);
    gemm_bt<1><<<gg, blk, 0, stream>>>(aws, wo, out);
}

// Round 4
// 155.214 us; speedup vs baseline: 2.0599x; 2.0599x over previous
//
#include <hip/hip_runtime.h>
#include <hip/hip_bf16.h>
#include <stdint.h>

#define S_LEN 2048
#define DM    1024
#define NH    16
#define DK    64
#define NBATCH 2

typedef __attribute__((ext_vector_type(8))) short bf8_t;   // 8 bf16 (4 VGPRs)
typedef __attribute__((ext_vector_type(4))) short s4_t;    // 4 bf16 (8B)
typedef __attribute__((ext_vector_type(4))) float f4_t;    // MFMA accum

using bf16 = __hip_bfloat16;

#define NEG_BIG (-1.0e30f)

static __device__ __forceinline__ f4_t mfma16(bf8_t a, bf8_t b, f4_t c) {
    return __builtin_amdgcn_mfma_f32_16x16x32_bf16(a, b, c, 0, 0, 0);
}

static __device__ __forceinline__ short f2b(float f) {
    __hip_bfloat16 h = __float2bfloat16(f);
    return *reinterpret_cast<short*>(&h);
}

// ---------------------------------------------------------------------------
// Fused QKV GEMM: C = x @ W^T, W selected by blockIdx.z (0=Q,1=K,2=V).
// x fp32 [4096,1024], W fp32 [1024,1024].
// z=0/1: C bf16 scattered head-major [B,H,S,DK] (Q,K)
// z=2  : C bf16 written TRANSPOSED per head [B,H,DK,S] (Vt) via packed b64
// 128x128 tile, BK=32, 4 waves (2x2), each wave 64x64 = 4x4 16x16 frags.
// ---------------------------------------------------------------------------
__global__ __launch_bounds__(256)
void gemm_qkv(const float* __restrict__ x,
              const float* __restrict__ wqp, const float* __restrict__ wkp,
              const float* __restrict__ wvp,
              bf16* __restrict__ qws, bf16* __restrict__ kws,
              bf16* __restrict__ vtws) {
    constexpr int K = DM;
    constexpr int BM = 128, BK = 32, LDT = BK + 8;

    const int z = blockIdx.z;
    const float* W = (z == 0) ? wqp : (z == 1) ? wkp : wvp;

    __shared__ bf16 As[BM][LDT];
    __shared__ bf16 Bs[BM][LDT];

    const int tid  = threadIdx.x;
    const int lane = tid & 63;
    const int w    = tid >> 6;
    const int wr   = w >> 1, wc = w & 1;
    const int lhi  = lane >> 4, llo = lane & 15;
    const int bm   = blockIdx.x * BM;
    const int bn   = blockIdx.y * BM;

    f4_t acc[4][4] = {};

    for (int k0 = 0; k0 < K; k0 += BK) {
        __syncthreads();
        #pragma unroll
        for (int t = 0; t < 2; ++t) {
            int c   = t * 256 + tid;
            int row = c >> 2;
            int col = (c & 3) << 3;
            {
                const float* s0 = x + (size_t)(bm + row) * K + k0 + col;
                float4 f0 = *(const float4*)(s0);
                float4 f1 = *(const float4*)(s0 + 4);
                bf8_t a8;
                a8[0]=f2b(f0.x); a8[1]=f2b(f0.y); a8[2]=f2b(f0.z); a8[3]=f2b(f0.w);
                a8[4]=f2b(f1.x); a8[5]=f2b(f1.y); a8[6]=f2b(f1.z); a8[7]=f2b(f1.w);
                *(bf8_t*)(&As[row][col]) = a8;
            }
            {
                const float* s0 = W + (size_t)(bn + row) * K + k0 + col;
                float4 f0 = *(const float4*)(s0);
                float4 f1 = *(const float4*)(s0 + 4);
                bf8_t b8;
                b8[0]=f2b(f0.x); b8[1]=f2b(f0.y); b8[2]=f2b(f0.z); b8[3]=f2b(f0.w);
                b8[4]=f2b(f1.x); b8[5]=f2b(f1.y); b8[6]=f2b(f1.z); b8[7]=f2b(f1.w);
                *(bf8_t*)(&Bs[row][col]) = b8;
            }
        }
        __syncthreads();

        bf8_t af[4], bfr[4];
        #pragma unroll
        for (int i = 0; i < 4; ++i) {
            af[i]  = *(const bf8_t*)(&As[wr * 64 + i * 16 + llo][lhi * 8]);
            bfr[i] = *(const bf8_t*)(&Bs[wc * 64 + i * 16 + llo][lhi * 8]);
        }
        #pragma unroll
        for (int mi = 0; mi < 4; ++mi)
            #pragma unroll
            for (int ni = 0; ni < 4; ++ni)
                acc[mi][ni] = mfma16(af[mi], bfr[ni], acc[mi][ni]);
    }

    if (z < 2) {
        bf16* C = z ? kws : qws;
        #pragma unroll
        for (int mi = 0; mi < 4; ++mi)
            #pragma unroll
            for (int ni = 0; ni < 4; ++ni)
                #pragma unroll
                for (int r = 0; r < 4; ++r) {
                    int m = bm + wr * 64 + mi * 16 + lhi * 4 + r;
                    int n = bn + wc * 64 + ni * 16 + llo;
                    int b = m >> 11, s = m & (S_LEN - 1);
                    int h = n >> 6,  d = n & (DK - 1);
                    C[(((size_t)(b * NH + h) * S_LEN) + s) * DK + d] =
                        __float2bfloat16(acc[mi][ni][r]);
                }
    } else {
        // Vt: [B,H,DK,S]; lane packs 4 consecutive s (r=0..3) into one b64
        #pragma unroll
        for (int mi = 0; mi < 4; ++mi)
            #pragma unroll
            for (int ni = 0; ni < 4; ++ni) {
                int m0 = bm + wr * 64 + mi * 16 + lhi * 4;
                int n  = bn + wc * 64 + ni * 16 + llo;
                int b = m0 >> 11, s0 = m0 & (S_LEN - 1);
                int h = n >> 6,   d  = n & (DK - 1);
                s4_t pk;
                #pragma unroll
                for (int r = 0; r < 4; ++r) pk[r] = f2b(acc[mi][ni][r]);
                *(s4_t*)&vtws[(((size_t)(b * NH + h) * DK) + d) * S_LEN + s0] = pk;
            }
    }
}

// ---------------------------------------------------------------------------
// O-projection GEMM: A bf16 [4096,1024] (attn out), W fp32, C fp32 row-major.
// ---------------------------------------------------------------------------
__global__ __launch_bounds__(256)
void gemm_o(const bf16* __restrict__ A, const float* __restrict__ W,
            float* __restrict__ C) {
    constexpr int N = DM;
    constexpr int K = DM;
    constexpr int BM = 128, BK = 32, LDT = BK + 8;

    __shared__ bf16 As[BM][LDT];
    __shared__ bf16 Bs[BM][LDT];

    const int tid  = threadIdx.x;
    const int lane = tid & 63;
    const int w    = tid >> 6;
    const int wr   = w >> 1, wc = w & 1;
    const int lhi  = lane >> 4, llo = lane & 15;
    const int bm   = blockIdx.x * BM;
    const int bn   = blockIdx.y * BM;

    f4_t acc[4][4] = {};

    for (int k0 = 0; k0 < K; k0 += BK) {
        __syncthreads();
        #pragma unroll
        for (int t = 0; t < 2; ++t) {
            int c   = t * 256 + tid;
            int row = c >> 2;
            int col = (c & 3) << 3;
            *(bf8_t*)(&As[row][col]) =
                *(const bf8_t*)(A + (size_t)(bm + row) * K + k0 + col);
            const float* s0 = W + (size_t)(bn + row) * K + k0 + col;
            float4 f0 = *(const float4*)(s0);
            float4 f1 = *(const float4*)(s0 + 4);
            bf8_t b8;
            b8[0]=f2b(f0.x); b8[1]=f2b(f0.y); b8[2]=f2b(f0.z); b8[3]=f2b(f0.w);
            b8[4]=f2b(f1.x); b8[5]=f2b(f1.y); b8[6]=f2b(f1.z); b8[7]=f2b(f1.w);
            *(bf8_t*)(&Bs[row][col]) = b8;
        }
        __syncthreads();

        bf8_t af[4], bfr[4];
        #pragma unroll
        for (int i = 0; i < 4; ++i) {
            af[i]  = *(const bf8_t*)(&As[wr * 64 + i * 16 + llo][lhi * 8]);
            bfr[i] = *(const bf8_t*)(&Bs[wc * 64 + i * 16 + llo][lhi * 8]);
        }
        #pragma unroll
        for (int mi = 0; mi < 4; ++mi)
            #pragma unroll
            for (int ni = 0; ni < 4; ++ni)
                acc[mi][ni] = mfma16(af[mi], bfr[ni], acc[mi][ni]);
    }

    #pragma unroll
    for (int mi = 0; mi < 4; ++mi)
        #pragma unroll
        for (int ni = 0; ni < 4; ++ni)
            #pragma unroll
            for (int r = 0; r < 4; ++r) {
                int m = bm + wr * 64 + mi * 16 + lhi * 4 + r;
                int n = bn + wc * 64 + ni * 16 + llo;
                C[(size_t)m * N + n] = acc[mi][ni][r];
            }
}

// ---------------------------------------------------------------------------
// Causal flash attention. 256 thr = 4 waves, 64-q-row tile per call.
// Block processes paired q-tiles (bx, 31-bx) -> uniform 33 KV-tile-steps.
// K head-major [B,H,S,DK]; V pre-transposed [B,H,DK,S].
// Double-buffered K/V staging, ONE barrier per KV tile.
// ---------------------------------------------------------------------------
__device__ __forceinline__ void process_qtile(
    int qt, int bh, int tid,
    const bf16* __restrict__ Qh, const bf16* __restrict__ Kh,
    const bf16* __restrict__ Vh, bf16* __restrict__ AO,
    bf16 (*Ks)[64][72], bf16 (*Vs)[64][72], bf16 (*Pl)[16][72]) {

    const int lane = tid & 63;
    const int w    = tid >> 6;
    const int lhi  = lane >> 4, llo = lane & 15;
    const int q0   = qt * 64;
    const int nt   = qt + 1;

    const int srow = tid >> 3;          // 0..31 rows? no: 256/8 = 32.. see below
    // staging: 256 threads, tile is 64 rows x 64 cols of bf16, 8-elem chunks:
    // 64*8 = 512 chunks -> 2 per thread. chunk c: row=c>>3, col=(c&7)*8
    const int scol = (tid & 7) << 3;

    // Q A-frags
    const bf16* qrow = Qh + (size_t)(q0 + w * 16 + llo) * DK;
    const bf8_t qf0 = *(const bf8_t*)(qrow + lhi * 8);
    const bf8_t qf1 = *(const bf8_t*)(qrow + 32 + lhi * 8);

    // prologue: stage tile 0 (both halves)
    {
        int r0 = tid >> 3;              // 0..31
        *(bf8_t*)&Ks[0][r0][scol]      = *(const bf8_t*)(Kh + (size_t)r0 * DK + scol);
        *(bf8_t*)&Ks[0][r0 + 32][scol] = *(const bf8_t*)(Kh + (size_t)(r0 + 32) * DK + scol);
        *(bf8_t*)&Vs[0][r0][scol]      = *(const bf8_t*)(Vh + (size_t)r0 * S_LEN + scol);
        *(bf8_t*)&Vs[0][r0 + 32][scol] = *(const bf8_t*)(Vh + (size_t)(r0 + 32) * S_LEN + scol);
    }
    __syncthreads();

    f4_t o[4] = {};
    float mr[4], lr[4];
    #pragma unroll
    for (int r = 0; r < 4; ++r) { mr[r] = NEG_BIG; lr[r] = 0.f; }
    const float scale = 0.125f;

    bf8_t kr0, kr1, vr0, vr1;

    for (int t = 0; t < nt; ++t) {
        const int kv0 = t * 64;
        const int cur = t & 1;
        const int r0  = tid >> 3;

        if (t + 1 < nt) {   // issue next-tile loads early (hide under compute)
            kr0 = *(const bf8_t*)(Kh + (size_t)(kv0 + 64 + r0) * DK + scol);
            kr1 = *(const bf8_t*)(Kh + (size_t)(kv0 + 96 + r0) * DK + scol);
            vr0 = *(const bf8_t*)(Vh + (size_t)r0 * S_LEN + kv0 + 64 + scol);
            vr1 = *(const bf8_t*)(Vh + (size_t)(r0 + 32) * S_LEN + kv0 + 64 + scol);
        }

        // QK^T
        f4_t s[4] = {};
        #pragma unroll
        for (int nf = 0; nf < 4; ++nf) {
            bf8_t k0f = *(const bf8_t*)&Ks[cur][nf * 16 + llo][lhi * 8];
            bf8_t k1f = *(const bf8_t*)&Ks[cur][nf * 16 + llo][32 + lhi * 8];
            s[nf] = mfma16(qf0, k0f, s[nf]);
            s[nf] = mfma16(qf1, k1f, s[nf]);
        }

        const bool diag = (kv0 == q0);
        #pragma unroll
        for (int nf = 0; nf < 4; ++nf)
            #pragma unroll
            for (int r = 0; r < 4; ++r) {
                float v = s[nf][r] * scale;
                if (diag && (nf * 16 + llo) > (w * 16 + lhi * 4 + r))
                    v = NEG_BIG;
                s[nf][r] = v;
            }

        float pm[4];
        #pragma unroll
        for (int r = 0; r < 4; ++r)
            pm[r] = fmaxf(fmaxf(s[0][r], s[1][r]), fmaxf(s[2][r], s[3][r]));
        #pragma unroll
        for (int off = 1; off < 16; off <<= 1)
            #pragma unroll
            for (int r = 0; r < 4; ++r)
                pm[r] = fmaxf(pm[r], __shfl_xor(pm[r], off));

        float alpha[4];
        #pragma unroll
        for (int r = 0; r < 4; ++r) {
            float mn = fmaxf(mr[r], pm[r]);
            alpha[r] = __expf(mr[r] - mn);
            mr[r] = mn;
        }

        float rs[4] = {0.f, 0.f, 0.f, 0.f};
        #pragma unroll
        for (int nf = 0; nf < 4; ++nf)
            #pragma unroll
            for (int r = 0; r < 4; ++r) {
                float p = __expf(s[nf][r] - mr[r]);
                rs[r] += p;
                Pl[w][lhi * 4 + r][nf * 16 + llo] = __float2bfloat16(p);
            }
        #pragma unroll
        for (int off = 1; off < 16; off <<= 1)
            #pragma unroll
            for (int r = 0; r < 4; ++r)
                rs[r] += __shfl_xor(rs[r], off);
        #pragma unroll
        for (int r = 0; r < 4; ++r) lr[r] = lr[r] * alpha[r] + rs[r];
        #pragma unroll
        for (int df = 0; df < 4; ++df)
            #pragma unroll
            for (int r = 0; r < 4; ++r) o[df][r] *= alpha[r];

        // wave-local P handoff (rule #18: waitcnt + sched_barrier)
        asm volatile("s_waitcnt lgkmcnt(0)" ::: "memory");
        __builtin_amdgcn_sched_barrier(0);

        #pragma unroll
        for (int df = 0; df < 4; ++df)
            #pragma unroll
            for (int kk = 0; kk < 2; ++kk) {
                bf8_t pa = *(const bf8_t*)&Pl[w][llo][kk * 32 + lhi * 8];
                bf8_t vb = *(const bf8_t*)&Vs[cur][df * 16 + llo][kk * 32 + lhi * 8];
                o[df] = mfma16(pa, vb, o[df]);
            }

        if (t + 1 < nt) {   // write next tile into other buffer, then barrier
            *(bf8_t*)&Ks[cur ^ 1][r0][scol]      = kr0;
            *(bf8_t*)&Ks[cur ^ 1][r0 + 32][scol] = kr1;
            *(bf8_t*)&Vs[cur ^ 1][r0][scol]      = vr0;
            *(bf8_t*)&Vs[cur ^ 1][r0 + 32][scol] = vr1;
        }
        __syncthreads();
    }

    const int b = bh >> 4, h = bh & (NH - 1);
    #pragma unroll
    for (int r = 0; r < 4; ++r) {
        float inv = 1.0f / lr[r];
        int q = q0 + w * 16 + lhi * 4 + r;
        bf16* orow = AO + ((size_t)(b * S_LEN + q) * DM) + h * DK;
        #pragma unroll
        for (int df = 0; df < 4; ++df)
            orow[df * 16 + llo] = __float2bfloat16(o[df][r] * inv);
    }
}

__global__ __launch_bounds__(256, 3)
void attn_fwd(const bf16* __restrict__ Q, const bf16* __restrict__ K,
              const bf16* __restrict__ Vt, bf16* __restrict__ AO) {
    __shared__ bf16 Ks[2][64][72];
    __shared__ bf16 Vs[2][64][72];
    __shared__ bf16 Pl[4][16][72];

    const int bx = blockIdx.x;
    const int bh = blockIdx.y;
    const bf16* Qh = Q  + (size_t)bh * S_LEN * DK;
    const bf16* Kh = K  + (size_t)bh * S_LEN * DK;
    const bf16* Vh = Vt + (size_t)bh * DK * S_LEN;

    process_qtile(31 - bx, bh, threadIdx.x, Qh, Kh, Vh, AO, Ks, Vs, Pl);
    process_qtile(bx,      bh, threadIdx.x, Qh, Kh, Vh, AO, Ks, Vs, Pl);
}

// ---------------------------------------------------------------------------
extern "C" void kernel_launch(void* const* d_in, const int* in_sizes, int n_in,
                              void* d_out, int out_size, void* d_ws, size_t ws_size,
                              hipStream_t stream) {
    const float* x  = (const float*)d_in[0];
    const float* wq = (const float*)d_in[1];
    const float* wk = (const float*)d_in[2];
    const float* wv = (const float*)d_in[3];
    const float* wo = (const float*)d_in[4];
    float* out = (float*)d_out;

    const size_t elems = (size_t)NBATCH * S_LEN * DM;  // 4,194,304
    if (ws_size < elems * 4 * sizeof(bf16)) return;

    bf16* qws  = (bf16*)d_ws;
    bf16* kws  = qws + elems;
    bf16* vtws = kws + elems;   // [B,H,DK,S]
    bf16* aws  = vtws + elems;

    dim3 blk(256);
    gemm_qkv<<<dim3(32, 8, 3), blk, 0, stream>>>(x, wq, wk, wv, qws, kws, vtws);
    attn_fwd<<<dim3(16, NBATCH * NH), blk, 0, stream>>>(qws, kws, vtws, aws);
    gemm_o<<<dim3(32, 8), blk, 0, stream>>>(aws, wo, out);
}

// Round 5
// 137.063 us; speedup vs baseline: 2.3327x; 1.1324x over previous
//
#include <hip/hip_runtime.h>
#include <hip/hip_bf16.h>
#include <stdint.h>

#define S_LEN 2048
#define DM    1024
#define NH    16
#define DK    64
#define NBATCH 2

typedef __attribute__((ext_vector_type(8))) short bf8_t;   // 8 bf16 (4 VGPRs)
typedef __attribute__((ext_vector_type(4))) short s4_t;    // 4 bf16 (8B)
typedef __attribute__((ext_vector_type(4))) float f4_t;    // MFMA accum

using bf16 = __hip_bfloat16;

#define NEG_BIG (-1.0e30f)

static __device__ __forceinline__ f4_t mfma16(bf8_t a, bf8_t b, f4_t c) {
    return __builtin_amdgcn_mfma_f32_16x16x32_bf16(a, b, c, 0, 0, 0);
}

static __device__ __forceinline__ short f2b(float f) {
    __hip_bfloat16 h = __float2bfloat16(f);
    return *reinterpret_cast<short*>(&h);
}

// ---------------------------------------------------------------------------
// Fused QKV GEMM: C = x @ W^T, W selected by blockIdx.z (0=Q,1=K,2=V).
// z=0/1: C bf16 scattered head-major [B,H,S,DK] (Q,K)
// z=2  : C bf16 written TRANSPOSED per head [B,H,DK,S] (Vt) via packed b64
// ---------------------------------------------------------------------------
__global__ __launch_bounds__(256)
void gemm_qkv(const float* __restrict__ x,
              const float* __restrict__ wqp, const float* __restrict__ wkp,
              const float* __restrict__ wvp,
              bf16* __restrict__ qws, bf16* __restrict__ kws,
              bf16* __restrict__ vtws) {
    constexpr int K = DM;
    constexpr int BM = 128, BK = 32, LDT = BK + 8;

    const int z = blockIdx.z;
    const float* W = (z == 0) ? wqp : (z == 1) ? wkp : wvp;

    __shared__ bf16 As[BM][LDT];
    __shared__ bf16 Bs[BM][LDT];

    const int tid  = threadIdx.x;
    const int lane = tid & 63;
    const int w    = tid >> 6;
    const int wr   = w >> 1, wc = w & 1;
    const int lhi  = lane >> 4, llo = lane & 15;
    const int bm   = blockIdx.x * BM;
    const int bn   = blockIdx.y * BM;

    f4_t acc[4][4] = {};

    for (int k0 = 0; k0 < K; k0 += BK) {
        __syncthreads();
        #pragma unroll
        for (int t = 0; t < 2; ++t) {
            int c   = t * 256 + tid;
            int row = c >> 2;
            int col = (c & 3) << 3;
            {
                const float* s0 = x + (size_t)(bm + row) * K + k0 + col;
                float4 f0 = *(const float4*)(s0);
                float4 f1 = *(const float4*)(s0 + 4);
                bf8_t a8;
                a8[0]=f2b(f0.x); a8[1]=f2b(f0.y); a8[2]=f2b(f0.z); a8[3]=f2b(f0.w);
                a8[4]=f2b(f1.x); a8[5]=f2b(f1.y); a8[6]=f2b(f1.z); a8[7]=f2b(f1.w);
                *(bf8_t*)(&As[row][col]) = a8;
            }
            {
                const float* s0 = W + (size_t)(bn + row) * K + k0 + col;
                float4 f0 = *(const float4*)(s0);
                float4 f1 = *(const float4*)(s0 + 4);
                bf8_t b8;
                b8[0]=f2b(f0.x); b8[1]=f2b(f0.y); b8[2]=f2b(f0.z); b8[3]=f2b(f0.w);
                b8[4]=f2b(f1.x); b8[5]=f2b(f1.y); b8[6]=f2b(f1.z); b8[7]=f2b(f1.w);
                *(bf8_t*)(&Bs[row][col]) = b8;
            }
        }
        __syncthreads();

        bf8_t af[4], bfr[4];
        #pragma unroll
        for (int i = 0; i < 4; ++i) {
            af[i]  = *(const bf8_t*)(&As[wr * 64 + i * 16 + llo][lhi * 8]);
            bfr[i] = *(const bf8_t*)(&Bs[wc * 64 + i * 16 + llo][lhi * 8]);
        }
        #pragma unroll
        for (int mi = 0; mi < 4; ++mi)
            #pragma unroll
            for (int ni = 0; ni < 4; ++ni)
                acc[mi][ni] = mfma16(af[mi], bfr[ni], acc[mi][ni]);
    }

    if (z < 2) {
        bf16* C = z ? kws : qws;
        #pragma unroll
        for (int mi = 0; mi < 4; ++mi)
            #pragma unroll
            for (int ni = 0; ni < 4; ++ni)
                #pragma unroll
                for (int r = 0; r < 4; ++r) {
                    int m = bm + wr * 64 + mi * 16 + lhi * 4 + r;
                    int n = bn + wc * 64 + ni * 16 + llo;
                    int b = m >> 11, s = m & (S_LEN - 1);
                    int h = n >> 6,  d = n & (DK - 1);
                    C[(((size_t)(b * NH + h) * S_LEN) + s) * DK + d] =
                        __float2bfloat16(acc[mi][ni][r]);
                }
    } else {
        #pragma unroll
        for (int mi = 0; mi < 4; ++mi)
            #pragma unroll
            for (int ni = 0; ni < 4; ++ni) {
                int m0 = bm + wr * 64 + mi * 16 + lhi * 4;
                int n  = bn + wc * 64 + ni * 16 + llo;
                int b = m0 >> 11, s0 = m0 & (S_LEN - 1);
                int h = n >> 6,   d  = n & (DK - 1);
                s4_t pk;
                #pragma unroll
                for (int r = 0; r < 4; ++r) pk[r] = f2b(acc[mi][ni][r]);
                *(s4_t*)&vtws[(((size_t)(b * NH + h) * DK) + d) * S_LEN + s0] = pk;
            }
    }
}

// ---------------------------------------------------------------------------
// O-projection GEMM: A bf16 [4096,1024], W fp32, C fp32 row-major.
// 128x64 tile -> 512 blocks (2/CU). 4 waves 2x2; wave-tile 64x32.
// ---------------------------------------------------------------------------
__global__ __launch_bounds__(256)
void gemm_o(const bf16* __restrict__ A, const float* __restrict__ W,
            float* __restrict__ C) {
    constexpr int N = DM;
    constexpr int K = DM;
    constexpr int BM = 128, BN = 64, BK = 32, LDT = BK + 8;

    __shared__ bf16 As[BM][LDT];
    __shared__ bf16 Bs[BN][LDT];

    const int tid  = threadIdx.x;
    const int lane = tid & 63;
    const int w    = tid >> 6;
    const int wr   = w >> 1, wc = w & 1;
    const int lhi  = lane >> 4, llo = lane & 15;
    const int bm   = blockIdx.x * BM;
    const int bn   = blockIdx.y * BN;

    f4_t acc[4][2] = {};

    for (int k0 = 0; k0 < K; k0 += BK) {
        __syncthreads();
        #pragma unroll
        for (int t = 0; t < 2; ++t) {
            int c   = t * 256 + tid;
            int row = c >> 2;
            int col = (c & 3) << 3;
            *(bf8_t*)(&As[row][col]) =
                *(const bf8_t*)(A + (size_t)(bm + row) * K + k0 + col);
        }
        {
            int row = tid >> 2;
            int col = (tid & 3) << 3;
            const float* s0 = W + (size_t)(bn + row) * K + k0 + col;
            float4 f0 = *(const float4*)(s0);
            float4 f1 = *(const float4*)(s0 + 4);
            bf8_t b8;
            b8[0]=f2b(f0.x); b8[1]=f2b(f0.y); b8[2]=f2b(f0.z); b8[3]=f2b(f0.w);
            b8[4]=f2b(f1.x); b8[5]=f2b(f1.y); b8[6]=f2b(f1.z); b8[7]=f2b(f1.w);
            *(bf8_t*)(&Bs[row][col]) = b8;
        }
        __syncthreads();

        bf8_t af[4], bfr[2];
        #pragma unroll
        for (int i = 0; i < 4; ++i)
            af[i] = *(const bf8_t*)(&As[wr * 64 + i * 16 + llo][lhi * 8]);
        #pragma unroll
        for (int i = 0; i < 2; ++i)
            bfr[i] = *(const bf8_t*)(&Bs[wc * 32 + i * 16 + llo][lhi * 8]);
        #pragma unroll
        for (int mi = 0; mi < 4; ++mi)
            #pragma unroll
            for (int ni = 0; ni < 2; ++ni)
                acc[mi][ni] = mfma16(af[mi], bfr[ni], acc[mi][ni]);
    }

    #pragma unroll
    for (int mi = 0; mi < 4; ++mi)
        #pragma unroll
        for (int ni = 0; ni < 2; ++ni)
            #pragma unroll
            for (int r = 0; r < 4; ++r) {
                int m = bm + wr * 64 + mi * 16 + lhi * 4 + r;
                int n = bn + wc * 32 + ni * 16 + llo;
                C[(size_t)m * N + n] = acc[mi][ni][r];
            }
}

// ---------------------------------------------------------------------------
// Causal flash attention. One 64-row q-tile per block; grid (bh=32, 32) with
// qt = 31 - blockIdx.y so the longest blocks dispatch first (global
// longest-first order -> short blocks backfill the tail).
// Softmax in exp2 domain; row-sum via MFMA against ones; setprio on MFMA.
// ---------------------------------------------------------------------------
__global__ __launch_bounds__(256, 3)
void attn_fwd(const bf16* __restrict__ Q, const bf16* __restrict__ K,
              const bf16* __restrict__ Vt, bf16* __restrict__ AO) {
    __shared__ bf16 Ks[2][64][72];
    __shared__ bf16 Vs[2][64][72];   // [d][kv] (V pre-transposed in HBM)
    __shared__ bf16 Pl[4][16][72];

    const int bh = blockIdx.x;
    const int qt = 31 - (int)blockIdx.y;
    const int q0 = qt * 64;
    const int nt = qt + 1;

    const bf16* Qh = Q  + (size_t)bh * S_LEN * DK;
    const bf16* Kh = K  + (size_t)bh * S_LEN * DK;
    const bf16* Vh = Vt + (size_t)bh * DK * S_LEN;

    const int tid  = threadIdx.x;
    const int lane = tid & 63;
    const int w    = tid >> 6;
    const int lhi  = lane >> 4, llo = lane & 15;
    const int r0   = tid >> 3;           // 0..31 staging row
    const int scol = (tid & 7) << 3;     // staging col (8-elem chunk)

    // Q A-frags
    const bf16* qrow = Qh + (size_t)(q0 + w * 16 + llo) * DK;
    const bf8_t qf0 = *(const bf8_t*)(qrow + lhi * 8);
    const bf8_t qf1 = *(const bf8_t*)(qrow + 32 + lhi * 8);

    // ones fragment for MFMA row-sum
    bf8_t ones;
    #pragma unroll
    for (int j = 0; j < 8; ++j) ones[j] = (short)0x3F80;

    // prologue: stage tile 0
    *(bf8_t*)&Ks[0][r0][scol]      = *(const bf8_t*)(Kh + (size_t)r0 * DK + scol);
    *(bf8_t*)&Ks[0][r0 + 32][scol] = *(const bf8_t*)(Kh + (size_t)(r0 + 32) * DK + scol);
    *(bf8_t*)&Vs[0][r0][scol]      = *(const bf8_t*)(Vh + (size_t)r0 * S_LEN + scol);
    *(bf8_t*)&Vs[0][r0 + 32][scol] = *(const bf8_t*)(Vh + (size_t)(r0 + 32) * S_LEN + scol);
    __syncthreads();

    f4_t o[4] = {};
    float mr[4], lr[4];
    #pragma unroll
    for (int r = 0; r < 4; ++r) { mr[r] = NEG_BIG; lr[r] = 0.f; }
    const float scale2 = 0.125f * 1.44269504088896f;   // 1/sqrt(dk) * log2(e)

    bf8_t kr0, kr1, vr0, vr1;

    for (int t = 0; t < nt; ++t) {
        const int kv0 = t * 64;
        const int cur = t & 1;

        if (t + 1 < nt) {   // issue next-tile loads early
            kr0 = *(const bf8_t*)(Kh + (size_t)(kv0 + 64 + r0) * DK + scol);
            kr1 = *(const bf8_t*)(Kh + (size_t)(kv0 + 96 + r0) * DK + scol);
            vr0 = *(const bf8_t*)(Vh + (size_t)r0 * S_LEN + kv0 + 64 + scol);
            vr1 = *(const bf8_t*)(Vh + (size_t)(r0 + 32) * S_LEN + kv0 + 64 + scol);
        }

        // QK^T
        f4_t s[4] = {};
        __builtin_amdgcn_s_setprio(1);
        #pragma unroll
        for (int nf = 0; nf < 4; ++nf) {
            bf8_t k0f = *(const bf8_t*)&Ks[cur][nf * 16 + llo][lhi * 8];
            bf8_t k1f = *(const bf8_t*)&Ks[cur][nf * 16 + llo][32 + lhi * 8];
            s[nf] = mfma16(qf0, k0f, s[nf]);
            s[nf] = mfma16(qf1, k1f, s[nf]);
        }
        __builtin_amdgcn_s_setprio(0);

        const bool diag = (kv0 == q0);
        #pragma unroll
        for (int nf = 0; nf < 4; ++nf)
            #pragma unroll
            for (int r = 0; r < 4; ++r) {
                float v = s[nf][r] * scale2;          // exp2 domain
                if (diag && (nf * 16 + llo) > (w * 16 + lhi * 4 + r))
                    v = NEG_BIG;
                s[nf][r] = v;
            }

        float pm[4];
        #pragma unroll
        for (int r = 0; r < 4; ++r)
            pm[r] = fmaxf(fmaxf(s[0][r], s[1][r]), fmaxf(s[2][r], s[3][r]));
        #pragma unroll
        for (int off = 1; off < 16; off <<= 1)
            #pragma unroll
            for (int r = 0; r < 4; ++r)
                pm[r] = fmaxf(pm[r], __shfl_xor(pm[r], off));

        float alpha[4];
        #pragma unroll
        for (int r = 0; r < 4; ++r) {
            float mn = fmaxf(mr[r], pm[r]);
            alpha[r] = exp2f(mr[r] - mn);
            mr[r] = mn;
        }

        // P = exp2(s - m) -> bf16 -> per-wave LDS
        #pragma unroll
        for (int nf = 0; nf < 4; ++nf)
            #pragma unroll
            for (int r = 0; r < 4; ++r)
                Pl[w][lhi * 4 + r][nf * 16 + llo] =
                    __float2bfloat16(exp2f(s[nf][r] - mr[r]));

        // rescale o while P writes land
        #pragma unroll
        for (int df = 0; df < 4; ++df)
            #pragma unroll
            for (int r = 0; r < 4; ++r) o[df][r] *= alpha[r];

        asm volatile("s_waitcnt lgkmcnt(0)" ::: "memory");
        __builtin_amdgcn_sched_barrier(0);

        bf8_t pa0 = *(const bf8_t*)&Pl[w][llo][lhi * 8];
        bf8_t pa1 = *(const bf8_t*)&Pl[w][llo][32 + lhi * 8];

        // row-sum via MFMA (all cols of rsacc equal the row sum)
        f4_t rsacc = {};
        rsacc = mfma16(pa0, ones, rsacc);
        rsacc = mfma16(pa1, ones, rsacc);

        __builtin_amdgcn_s_setprio(1);
        #pragma unroll
        for (int df = 0; df < 4; ++df) {
            bf8_t vb0 = *(const bf8_t*)&Vs[cur][df * 16 + llo][lhi * 8];
            bf8_t vb1 = *(const bf8_t*)&Vs[cur][df * 16 + llo][32 + lhi * 8];
            o[df] = mfma16(pa0, vb0, o[df]);
            o[df] = mfma16(pa1, vb1, o[df]);
        }
        __builtin_amdgcn_s_setprio(0);

        #pragma unroll
        for (int r = 0; r < 4; ++r) lr[r] = lr[r] * alpha[r] + rsacc[r];

        if (t + 1 < nt) {
            *(bf8_t*)&Ks[cur ^ 1][r0][scol]      = kr0;
            *(bf8_t*)&Ks[cur ^ 1][r0 + 32][scol] = kr1;
            *(bf8_t*)&Vs[cur ^ 1][r0][scol]      = vr0;
            *(bf8_t*)&Vs[cur ^ 1][r0 + 32][scol] = vr1;
        }
        __syncthreads();
    }

    const int b = bh >> 4, h = bh & (NH - 1);
    #pragma unroll
    for (int r = 0; r < 4; ++r) {
        float inv = 1.0f / lr[r];
        int q = q0 + w * 16 + lhi * 4 + r;
        bf16* orow = AO + ((size_t)(b * S_LEN + q) * DM) + h * DK;
        #pragma unroll
        for (int df = 0; df < 4; ++df)
            orow[df * 16 + llo] = __float2bfloat16(o[df][r] * inv);
    }
}

// ---------------------------------------------------------------------------
extern "C" void kernel_launch(void* const* d_in, const int* in_sizes, int n_in,
                              void* d_out, int out_size, void* d_ws, size_t ws_size,
                              hipStream_t stream) {
    const float* x  = (const float*)d_in[0];
    const float* wq = (const float*)d_in[1];
    const float* wk = (const float*)d_in[2];
    const float* wv = (const float*)d_in[3];
    const float* wo = (const float*)d_in[4];
    float* out = (float*)d_out;

    const size_t elems = (size_t)NBATCH * S_LEN * DM;
    if (ws_size < elems * 4 * sizeof(bf16)) return;

    bf16* qws  = (bf16*)d_ws;
    bf16* kws  = qws + elems;
    bf16* vtws = kws + elems;   // [B,H,DK,S]
    bf16* aws  = vtws + elems;

    dim3 blk(256);
    gemm_qkv<<<dim3(32, 8, 3), blk, 0, stream>>>(x, wq, wk, wv, qws, kws, vtws);
    attn_fwd<<<dim3(NBATCH * NH, 32), blk, 0, stream>>>(qws, kws, vtws, aws);
    gemm_o<<<dim3(32, 16), blk, 0, stream>>>(aws, wo, out);
}

// Round 6
// 124.599 us; speedup vs baseline: 2.5660x; 1.1000x over previous
//
#include <hip/hip_runtime.h>
#include <hip/hip_bf16.h>
#include <stdint.h>

#define S_LEN 2048
#define DM    1024
#define NH    16
#define DK    64
#define NBATCH 2

typedef __attribute__((ext_vector_type(8))) short bf8_t;   // 8 bf16 (4 VGPRs)
typedef __attribute__((ext_vector_type(4))) short s4_t;    // 4 bf16 (8B)
typedef __attribute__((ext_vector_type(4))) float f4_t;    // MFMA accum

using bf16 = __hip_bfloat16;

#define NEG_BIG (-1.0e30f)
#define SCALE2  (0.125f * 1.44269504088896f)   // 1/sqrt(dk) * log2(e)

static __device__ __forceinline__ f4_t mfma16(bf8_t a, bf8_t b, f4_t c) {
    return __builtin_amdgcn_mfma_f32_16x16x32_bf16(a, b, c, 0, 0, 0);
}

static __device__ __forceinline__ short f2b(float f) {
    __hip_bfloat16 h = __float2bfloat16(f);
    return *reinterpret_cast<short*>(&h);
}

// ---------------------------------------------------------------------------
// Fused QKV GEMM: C = x @ W^T, W selected by blockIdx.z (0=Q,1=K,2=V).
// z=0: Q, PRE-SCALED by 1/sqrt(dk)*log2e, bf16 head-major [B,H,S,DK]
// z=1: K, bf16 head-major [B,H,S,DK]
// z=2: V, bf16 TRANSPOSED per head [B,H,DK,S] via packed b64
// ---------------------------------------------------------------------------
__global__ __launch_bounds__(256)
void gemm_qkv(const float* __restrict__ x,
              const float* __restrict__ wqp, const float* __restrict__ wkp,
              const float* __restrict__ wvp,
              bf16* __restrict__ qws, bf16* __restrict__ kws,
              bf16* __restrict__ vtws) {
    constexpr int K = DM;
    constexpr int BM = 128, BK = 32, LDT = BK + 8;

    const int z = blockIdx.z;
    const float* W = (z == 0) ? wqp : (z == 1) ? wkp : wvp;

    __shared__ bf16 As[BM][LDT];
    __shared__ bf16 Bs[BM][LDT];

    const int tid  = threadIdx.x;
    const int lane = tid & 63;
    const int w    = tid >> 6;
    const int wr   = w >> 1, wc = w & 1;
    const int lhi  = lane >> 4, llo = lane & 15;
    const int bm   = blockIdx.x * BM;
    const int bn   = blockIdx.y * BM;

    f4_t acc[4][4] = {};

    for (int k0 = 0; k0 < K; k0 += BK) {
        __syncthreads();
        #pragma unroll
        for (int t = 0; t < 2; ++t) {
            int c   = t * 256 + tid;
            int row = c >> 2;
            int col = (c & 3) << 3;
            {
                const float* s0 = x + (size_t)(bm + row) * K + k0 + col;
                float4 f0 = *(const float4*)(s0);
                float4 f1 = *(const float4*)(s0 + 4);
                bf8_t a8;
                a8[0]=f2b(f0.x); a8[1]=f2b(f0.y); a8[2]=f2b(f0.z); a8[3]=f2b(f0.w);
                a8[4]=f2b(f1.x); a8[5]=f2b(f1.y); a8[6]=f2b(f1.z); a8[7]=f2b(f1.w);
                *(bf8_t*)(&As[row][col]) = a8;
            }
            {
                const float* s0 = W + (size_t)(bn + row) * K + k0 + col;
                float4 f0 = *(const float4*)(s0);
                float4 f1 = *(const float4*)(s0 + 4);
                bf8_t b8;
                b8[0]=f2b(f0.x); b8[1]=f2b(f0.y); b8[2]=f2b(f0.z); b8[3]=f2b(f0.w);
                b8[4]=f2b(f1.x); b8[5]=f2b(f1.y); b8[6]=f2b(f1.z); b8[7]=f2b(f1.w);
                *(bf8_t*)(&Bs[row][col]) = b8;
            }
        }
        __syncthreads();

        bf8_t af[4], bfr[4];
        #pragma unroll
        for (int i = 0; i < 4; ++i) {
            af[i]  = *(const bf8_t*)(&As[wr * 64 + i * 16 + llo][lhi * 8]);
            bfr[i] = *(const bf8_t*)(&Bs[wc * 64 + i * 16 + llo][lhi * 8]);
        }
        #pragma unroll
        for (int mi = 0; mi < 4; ++mi)
            #pragma unroll
            for (int ni = 0; ni < 4; ++ni)
                acc[mi][ni] = mfma16(af[mi], bfr[ni], acc[mi][ni]);
    }

    if (z < 2) {
        bf16* C = z ? kws : qws;
        const float sc = z ? 1.0f : SCALE2;    // fold attn scale into Q
        #pragma unroll
        for (int mi = 0; mi < 4; ++mi)
            #pragma unroll
            for (int ni = 0; ni < 4; ++ni)
                #pragma unroll
                for (int r = 0; r < 4; ++r) {
                    int m = bm + wr * 64 + mi * 16 + lhi * 4 + r;
                    int n = bn + wc * 64 + ni * 16 + llo;
                    int b = m >> 11, s = m & (S_LEN - 1);
                    int h = n >> 6,  d = n & (DK - 1);
                    C[(((size_t)(b * NH + h) * S_LEN) + s) * DK + d] =
                        __float2bfloat16(acc[mi][ni][r] * sc);
                }
    } else {
        #pragma unroll
        for (int mi = 0; mi < 4; ++mi)
            #pragma unroll
            for (int ni = 0; ni < 4; ++ni) {
                int m0 = bm + wr * 64 + mi * 16 + lhi * 4;
                int n  = bn + wc * 64 + ni * 16 + llo;
                int b = m0 >> 11, s0 = m0 & (S_LEN - 1);
                int h = n >> 6,   d  = n & (DK - 1);
                s4_t pk;
                #pragma unroll
                for (int r = 0; r < 4; ++r) pk[r] = f2b(acc[mi][ni][r]);
                *(s4_t*)&vtws[(((size_t)(b * NH + h) * DK) + d) * S_LEN + s0] = pk;
            }
    }
}

// ---------------------------------------------------------------------------
// O-projection GEMM: A bf16 [4096,1024], W fp32, C fp32 row-major.
// 128x64 tile -> 512 blocks (2/CU). 4 waves 2x2; wave-tile 64x32.
// ---------------------------------------------------------------------------
__global__ __launch_bounds__(256)
void gemm_o(const bf16* __restrict__ A, const float* __restrict__ W,
            float* __restrict__ C) {
    constexpr int N = DM;
    constexpr int K = DM;
    constexpr int BM = 128, BN = 64, BK = 32, LDT = BK + 8;

    __shared__ bf16 As[BM][LDT];
    __shared__ bf16 Bs[BN][LDT];

    const int tid  = threadIdx.x;
    const int lane = tid & 63;
    const int w    = tid >> 6;
    const int wr   = w >> 1, wc = w & 1;
    const int lhi  = lane >> 4, llo = lane & 15;
    const int bm   = blockIdx.x * BM;
    const int bn   = blockIdx.y * BN;

    f4_t acc[4][2] = {};

    for (int k0 = 0; k0 < K; k0 += BK) {
        __syncthreads();
        #pragma unroll
        for (int t = 0; t < 2; ++t) {
            int c   = t * 256 + tid;
            int row = c >> 2;
            int col = (c & 3) << 3;
            *(bf8_t*)(&As[row][col]) =
                *(const bf8_t*)(A + (size_t)(bm + row) * K + k0 + col);
        }
        {
            int row = tid >> 2;
            int col = (tid & 3) << 3;
            const float* s0 = W + (size_t)(bn + row) * K + k0 + col;
            float4 f0 = *(const float4*)(s0);
            float4 f1 = *(const float4*)(s0 + 4);
            bf8_t b8;
            b8[0]=f2b(f0.x); b8[1]=f2b(f0.y); b8[2]=f2b(f0.z); b8[3]=f2b(f0.w);
            b8[4]=f2b(f1.x); b8[5]=f2b(f1.y); b8[6]=f2b(f1.z); b8[7]=f2b(f1.w);
            *(bf8_t*)(&Bs[row][col]) = b8;
        }
        __syncthreads();

        bf8_t af[4], bfr[2];
        #pragma unroll
        for (int i = 0; i < 4; ++i)
            af[i] = *(const bf8_t*)(&As[wr * 64 + i * 16 + llo][lhi * 8]);
        #pragma unroll
        for (int i = 0; i < 2; ++i)
            bfr[i] = *(const bf8_t*)(&Bs[wc * 32 + i * 16 + llo][lhi * 8]);
        #pragma unroll
        for (int mi = 0; mi < 4; ++mi)
            #pragma unroll
            for (int ni = 0; ni < 2; ++ni)
                acc[mi][ni] = mfma16(af[mi], bfr[ni], acc[mi][ni]);
    }

    #pragma unroll
    for (int mi = 0; mi < 4; ++mi)
        #pragma unroll
        for (int ni = 0; ni < 2; ++ni)
            #pragma unroll
            for (int r = 0; r < 4; ++r) {
                int m = bm + wr * 64 + mi * 16 + lhi * 4 + r;
                int n = bn + wc * 32 + ni * 16 + llo;
                C[(size_t)m * N + n] = acc[mi][ni][r];
            }
}

// ---------------------------------------------------------------------------
// Causal flash attention, SWAPPED QK^T (S^T = K·Q^T): each lane owns ONE
// q-row (q=llo) x 16 kv values -> in-lane softmax reductions, packed b64
// P-stores. Q pre-scaled by 1/sqrt(dk)*log2e -> exp2-domain softmax, no
// per-score scaling. One 64-row q-tile per block; longest tiles first.
// ---------------------------------------------------------------------------
__global__ __launch_bounds__(256, 3)
void attn_fwd(const bf16* __restrict__ Q, const bf16* __restrict__ K,
              const bf16* __restrict__ Vt, bf16* __restrict__ AO) {
    __shared__ bf16 Ks[2][64][72];
    __shared__ bf16 Vs[2][64][72];   // [d][kv] (V pre-transposed in HBM)
    __shared__ bf16 Pl[4][16][72];   // per-wave P [q][kv]

    const int bh = blockIdx.x;
    const int qt = 31 - (int)blockIdx.y;
    const int q0 = qt * 64;
    const int nt = qt + 1;

    const bf16* Qh = Q  + (size_t)bh * S_LEN * DK;
    const bf16* Kh = K  + (size_t)bh * S_LEN * DK;
    const bf16* Vh = Vt + (size_t)bh * DK * S_LEN;

    const int tid  = threadIdx.x;
    const int lane = tid & 63;
    const int w    = tid >> 6;
    const int lhi  = lane >> 4, llo = lane & 15;
    const int r0   = tid >> 3;           // 0..31 staging row
    const int scol = (tid & 7) << 3;     // staging col (8-elem chunk)

    // Q B-frags (col = q = llo within wave tile)
    const bf16* qrow = Qh + (size_t)(q0 + w * 16 + llo) * DK;
    const bf8_t qf0 = *(const bf8_t*)(qrow + lhi * 8);
    const bf8_t qf1 = *(const bf8_t*)(qrow + 32 + lhi * 8);

    bf8_t ones;
    #pragma unroll
    for (int j = 0; j < 8; ++j) ones[j] = (short)0x3F80;

    // prologue: stage tile 0
    *(bf8_t*)&Ks[0][r0][scol]      = *(const bf8_t*)(Kh + (size_t)r0 * DK + scol);
    *(bf8_t*)&Ks[0][r0 + 32][scol] = *(const bf8_t*)(Kh + (size_t)(r0 + 32) * DK + scol);
    *(bf8_t*)&Vs[0][r0][scol]      = *(const bf8_t*)(Vh + (size_t)r0 * S_LEN + scol);
    *(bf8_t*)&Vs[0][r0 + 32][scol] = *(const bf8_t*)(Vh + (size_t)(r0 + 32) * S_LEN + scol);
    __syncthreads();

    f4_t o[4] = {};
    float lr[4] = {0.f, 0.f, 0.f, 0.f};   // o-layout (q = lhi*4+r)
    float mr = NEG_BIG;                    // per-lane, q = llo

    bf8_t kr0, kr1, vr0, vr1;

    for (int t = 0; t < nt; ++t) {
        const int kv0 = t * 64;
        const int cur = t & 1;

        if (t + 1 < nt) {   // issue next-tile loads early
            kr0 = *(const bf8_t*)(Kh + (size_t)(kv0 + 64 + r0) * DK + scol);
            kr1 = *(const bf8_t*)(Kh + (size_t)(kv0 + 96 + r0) * DK + scol);
            vr0 = *(const bf8_t*)(Vh + (size_t)r0 * S_LEN + kv0 + 64 + scol);
            vr1 = *(const bf8_t*)(Vh + (size_t)(r0 + 32) * S_LEN + kv0 + 64 + scol);
        }

        // S^T = K·Q^T: s[nf] rows = kv_local (nf*16+lhi*4+r), col = q (llo)
        f4_t s[4] = {};
        __builtin_amdgcn_s_setprio(1);
        #pragma unroll
        for (int nf = 0; nf < 4; ++nf) {
            bf8_t k0f = *(const bf8_t*)&Ks[cur][nf * 16 + llo][lhi * 8];
            bf8_t k1f = *(const bf8_t*)&Ks[cur][nf * 16 + llo][32 + lhi * 8];
            s[nf] = mfma16(k0f, qf0, s[nf]);
            s[nf] = mfma16(k1f, qf1, s[nf]);
        }
        __builtin_amdgcn_s_setprio(0);

        if (kv0 == q0) {                   // diagonal tile: causal mask
            const int qloc = w * 16 + llo;
            #pragma unroll
            for (int nf = 0; nf < 4; ++nf)
                #pragma unroll
                for (int r = 0; r < 4; ++r)
                    if (nf * 16 + lhi * 4 + r > qloc) s[nf][r] = NEG_BIG;
        }

        // row max: 15 in-lane fmax + 2-lane-group butterfly (lhi bits)
        float pm = s[0][0];
        #pragma unroll
        for (int nf = 0; nf < 4; ++nf)
            #pragma unroll
            for (int r = 0; r < 4; ++r) pm = fmaxf(pm, s[nf][r]);
        pm = fmaxf(pm, __shfl_xor(pm, 16));
        pm = fmaxf(pm, __shfl_xor(pm, 32));

        float mn = fmaxf(mr, pm);
        float alpha = exp2f(mr - mn);
        mr = mn;

        // P = exp2(s - mr): pack 4 bf16 -> one ds_write_b64 per nf
        #pragma unroll
        for (int nf = 0; nf < 4; ++nf) {
            s4_t pk;
            #pragma unroll
            for (int r = 0; r < 4; ++r) pk[r] = f2b(exp2f(s[nf][r] - mr));
            *(s4_t*)&Pl[w][llo][nf * 16 + lhi * 4] = pk;
        }

        // alpha to o-layout (q = lhi*4+r): bpermute from lane lhi*4+r
        float alpha_o[4];
        #pragma unroll
        for (int r = 0; r < 4; ++r) alpha_o[r] = __shfl(alpha, lhi * 4 + r);
        #pragma unroll
        for (int df = 0; df < 4; ++df)
            #pragma unroll
            for (int r = 0; r < 4; ++r) o[df][r] *= alpha_o[r];

        asm volatile("s_waitcnt lgkmcnt(0)" ::: "memory");
        __builtin_amdgcn_sched_barrier(0);

        bf8_t pa0 = *(const bf8_t*)&Pl[w][llo][lhi * 8];
        bf8_t pa1 = *(const bf8_t*)&Pl[w][llo][32 + lhi * 8];

        // row-sum via MFMA vs ones: rsacc[r] = sum_kv P[q=lhi*4+r][kv]
        f4_t rsacc = {};
        rsacc = mfma16(pa0, ones, rsacc);
        rsacc = mfma16(pa1, ones, rsacc);

        __builtin_amdgcn_s_setprio(1);
        #pragma unroll
        for (int df = 0; df < 4; ++df) {
            bf8_t vb0 = *(const bf8_t*)&Vs[cur][df * 16 + llo][lhi * 8];
            bf8_t vb1 = *(const bf8_t*)&Vs[cur][df * 16 + llo][32 + lhi * 8];
            o[df] = mfma16(pa0, vb0, o[df]);
            o[df] = mfma16(pa1, vb1, o[df]);
        }
        __builtin_amdgcn_s_setprio(0);

        #pragma unroll
        for (int r = 0; r < 4; ++r) lr[r] = lr[r] * alpha_o[r] + rsacc[r];

        if (t + 1 < nt) {
            *(bf8_t*)&Ks[cur ^ 1][r0][scol]      = kr0;
            *(bf8_t*)&Ks[cur ^ 1][r0 + 32][scol] = kr1;
            *(bf8_t*)&Vs[cur ^ 1][r0][scol]      = vr0;
            *(bf8_t*)&Vs[cur ^ 1][r0 + 32][scol] = vr1;
        }
        __syncthreads();
    }

    const int b = bh >> 4, h = bh & (NH - 1);
    #pragma unroll
    for (int r = 0; r < 4; ++r) {
        float inv = 1.0f / lr[r];
        int q = q0 + w * 16 + lhi * 4 + r;
        bf16* orow = AO + ((size_t)(b * S_LEN + q) * DM) + h * DK;
        #pragma unroll
        for (int df = 0; df < 4; ++df)
            orow[df * 16 + llo] = __float2bfloat16(o[df][r] * inv);
    }
}

// ---------------------------------------------------------------------------
extern "C" void kernel_launch(void* const* d_in, const int* in_sizes, int n_in,
                              void* d_out, int out_size, void* d_ws, size_t ws_size,
                              hipStream_t stream) {
    const float* x  = (const float*)d_in[0];
    const float* wq = (const float*)d_in[1];
    const float* wk = (const float*)d_in[2];
    const float* wv = (const float*)d_in[3];
    const float* wo = (const float*)d_in[4];
    float* out = (float*)d_out;

    const size_t elems = (size_t)NBATCH * S_LEN * DM;
    if (ws_size < elems * 4 * sizeof(bf16)) return;

    bf16* qws  = (bf16*)d_ws;
    bf16* kws  = qws + elems;
    bf16* vtws = kws + elems;   // [B,H,DK,S]
    bf16* aws  = vtws + elems;

    dim3 blk(256);
    gemm_qkv<<<dim3(32, 8, 3), blk, 0, stream>>>(x, wq, wk, wv, qws, kws, vtws);
    attn_fwd<<<dim3(NBATCH * NH, 32), blk, 0, stream>>>(qws, kws, vtws, aws);
    gemm_o<<<dim3(32, 16), blk, 0, stream>>>(aws, wo, out);
}

// Round 7
// 117.791 us; speedup vs baseline: 2.7144x; 1.0578x over previous
//
#include <hip/hip_runtime.h>
#include <hip/hip_bf16.h>
#include <stdint.h>

#define S_LEN 2048
#define DM    1024
#define NH    16
#define DK    64
#define NBATCH 2

typedef __attribute__((ext_vector_type(8))) short bf8_t;   // 8 bf16 (4 VGPRs)
typedef __attribute__((ext_vector_type(4))) short s4_t;    // 4 bf16 (8B)
typedef __attribute__((ext_vector_type(4))) float f4_t;    // MFMA accum

using bf16 = __hip_bfloat16;

#define NEG_BIG (-1.0e30f)
#define SCALE2  (0.125f * 1.44269504088896f)   // 1/sqrt(dk) * log2(e)

static __device__ __forceinline__ f4_t mfma16(bf8_t a, bf8_t b, f4_t c) {
    return __builtin_amdgcn_mfma_f32_16x16x32_bf16(a, b, c, 0, 0, 0);
}

static __device__ __forceinline__ short f2b(float f) {
    __hip_bfloat16 h = __float2bfloat16(f);
    return *reinterpret_cast<short*>(&h);
}

// async global->LDS, 16B per lane. Dest must be linear: uniform base + lane*16.
static __device__ __forceinline__ void g2l16(const bf16* g, bf16* l) {
#if __has_builtin(__builtin_amdgcn_global_load_lds)
    __builtin_amdgcn_global_load_lds(
        (const __attribute__((address_space(1))) void*)g,
        (__attribute__((address_space(3))) void*)l, 16, 0, 0);
#else
    *(bf8_t*)l = *(const bf8_t*)g;   // correct, slower
#endif
}

// ---------------------------------------------------------------------------
// fp32 -> bf16 pre-convert: ob = [xb 4M | wqb 1M | wkb 1M | wvb 1M | wob 1M]
// ---------------------------------------------------------------------------
__global__ __launch_bounds__(256)
void cvt_all(const float* __restrict__ x,  const float* __restrict__ wq,
             const float* __restrict__ wk, const float* __restrict__ wv,
             const float* __restrict__ wo, bf16* __restrict__ ob) {
    const size_t SEG = 1u << 20;
    size_t i = ((size_t)blockIdx.x * 256 + threadIdx.x) * 8;
    const float* src;
    if      (i < 4 * SEG) src = x  + i;
    else if (i < 5 * SEG) src = wq + (i - 4 * SEG);
    else if (i < 6 * SEG) src = wk + (i - 5 * SEG);
    else if (i < 7 * SEG) src = wv + (i - 6 * SEG);
    else                  src = wo + (i - 7 * SEG);
    float4 f0 = *(const float4*)(src);
    float4 f1 = *(const float4*)(src + 4);
    bf8_t v;
    v[0]=f2b(f0.x); v[1]=f2b(f0.y); v[2]=f2b(f0.z); v[3]=f2b(f0.w);
    v[4]=f2b(f1.x); v[5]=f2b(f1.y); v[6]=f2b(f1.z); v[7]=f2b(f1.w);
    *(bf8_t*)(ob + i) = v;
}

// ---------------------------------------------------------------------------
// bf16 GEMM main loop (m97 structure): 128x128 tile, BK=32, LINEAR LDS,
// global_load_lds width-16 staging, 4 waves 2x2, 4x4 16x16 frags.
// Shared between the two epilogues via a macro.
// ---------------------------------------------------------------------------
#define GEMM_B_MAINLOOP(Aptr, Bptr)                                          \
    __shared__ bf16 As[128][32];                                             \
    __shared__ bf16 Bs[128][32];                                             \
    const int tid  = threadIdx.x;                                            \
    const int lane = tid & 63;                                               \
    const int w    = tid >> 6;                                               \
    const int wr   = w >> 1, wc = w & 1;                                     \
    const int lhi  = lane >> 4, llo = lane & 15;                             \
    const int bm   = blockIdx.x * 128;                                       \
    const int bn   = blockIdx.y * 128;                                       \
    const int r0c  = tid >> 2;                 /* chunk row, t=0 */          \
    const int c0c  = (tid & 3) << 3;           /* chunk col      */          \
    const int r1c  = (256 + tid) >> 2;                                       \
    f4_t acc[4][4] = {};                                                     \
    for (int k0 = 0; k0 < 1024; k0 += 32) {                                  \
        __syncthreads();                                                     \
        g2l16(Aptr + (size_t)(bm + r0c) * 1024 + k0 + c0c,                   \
              &As[0][0] + (size_t)tid * 8);                                  \
        g2l16(Aptr + (size_t)(bm + r1c) * 1024 + k0 + c0c,                   \
              &As[0][0] + (size_t)(256 + tid) * 8);                          \
        g2l16(Bptr + (size_t)(bn + r0c) * 1024 + k0 + c0c,                   \
              &Bs[0][0] + (size_t)tid * 8);                                  \
        g2l16(Bptr + (size_t)(bn + r1c) * 1024 + k0 + c0c,                   \
              &Bs[0][0] + (size_t)(256 + tid) * 8);                          \
        asm volatile("s_waitcnt vmcnt(0)" ::: "memory");                     \
        __syncthreads();                                                     \
        bf8_t af[4], bfr[4];                                                 \
        _Pragma("unroll")                                                    \
        for (int i = 0; i < 4; ++i) {                                        \
            af[i]  = *(const bf8_t*)(&As[wr * 64 + i * 16 + llo][lhi * 8]);  \
            bfr[i] = *(const bf8_t*)(&Bs[wc * 64 + i * 16 + llo][lhi * 8]);  \
        }                                                                    \
        _Pragma("unroll")                                                    \
        for (int mi = 0; mi < 4; ++mi)                                       \
            _Pragma("unroll")                                                \
            for (int ni = 0; ni < 4; ++ni)                                   \
                acc[mi][ni] = mfma16(af[mi], bfr[ni], acc[mi][ni]);          \
    }

// QKV epilogue: z=0 Q (pre-scaled), z=1 K, z=2 V transposed [B,H,DK,S]
__global__ __launch_bounds__(256)
void gemm_qkv_b(const bf16* __restrict__ xb,
                const bf16* __restrict__ wqb, const bf16* __restrict__ wkb,
                const bf16* __restrict__ wvb,
                bf16* __restrict__ qws, bf16* __restrict__ kws,
                bf16* __restrict__ vtws) {
    const int z = blockIdx.z;
    const bf16* Wb = (z == 0) ? wqb : (z == 1) ? wkb : wvb;
    GEMM_B_MAINLOOP(xb, Wb)

    if (z < 2) {
        bf16* C = z ? kws : qws;
        const float sc = z ? 1.0f : SCALE2;
        #pragma unroll
        for (int mi = 0; mi < 4; ++mi)
            #pragma unroll
            for (int ni = 0; ni < 4; ++ni)
                #pragma unroll
                for (int r = 0; r < 4; ++r) {
                    int m = bm + wr * 64 + mi * 16 + lhi * 4 + r;
                    int n = bn + wc * 64 + ni * 16 + llo;
                    int b = m >> 11, s = m & (S_LEN - 1);
                    int h = n >> 6,  d = n & (DK - 1);
                    C[(((size_t)(b * NH + h) * S_LEN) + s) * DK + d] =
                        __float2bfloat16(acc[mi][ni][r] * sc);
                }
    } else {
        #pragma unroll
        for (int mi = 0; mi < 4; ++mi)
            #pragma unroll
            for (int ni = 0; ni < 4; ++ni) {
                int m0 = bm + wr * 64 + mi * 16 + lhi * 4;
                int n  = bn + wc * 64 + ni * 16 + llo;
                int b = m0 >> 11, s0 = m0 & (S_LEN - 1);
                int h = n >> 6,   d  = n & (DK - 1);
                s4_t pk;
                #pragma unroll
                for (int r = 0; r < 4; ++r) pk[r] = f2b(acc[mi][ni][r]);
                *(s4_t*)&vtws[(((size_t)(b * NH + h) * DK) + d) * S_LEN + s0] = pk;
            }
    }
}

// O-projection epilogue: fp32 row-major C
__global__ __launch_bounds__(256)
void gemm_o_b(const bf16* __restrict__ A, const bf16* __restrict__ Wb,
              float* __restrict__ C) {
    GEMM_B_MAINLOOP(A, Wb)
    #pragma unroll
    for (int mi = 0; mi < 4; ++mi)
        #pragma unroll
        for (int ni = 0; ni < 4; ++ni)
            #pragma unroll
            for (int r = 0; r < 4; ++r) {
                int m = bm + wr * 64 + mi * 16 + lhi * 4 + r;
                int n = bn + wc * 64 + ni * 16 + llo;
                C[(size_t)m * DM + n] = acc[mi][ni][r];
            }
}

// ---------------------------------------------------------------------------
// FALLBACK (small ws): round-6 inline-convert GEMMs
// ---------------------------------------------------------------------------
__global__ __launch_bounds__(256)
void gemm_qkv_f32(const float* __restrict__ x,
                  const float* __restrict__ wqp, const float* __restrict__ wkp,
                  const float* __restrict__ wvp,
                  bf16* __restrict__ qws, bf16* __restrict__ kws,
                  bf16* __restrict__ vtws) {
    constexpr int K = DM;
    constexpr int BM = 128, BK = 32, LDT = BK + 8;
    const int z = blockIdx.z;
    const float* W = (z == 0) ? wqp : (z == 1) ? wkp : wvp;
    __shared__ bf16 As[BM][LDT];
    __shared__ bf16 Bs[BM][LDT];
    const int tid  = threadIdx.x;
    const int lane = tid & 63;
    const int w    = tid >> 6;
    const int wr   = w >> 1, wc = w & 1;
    const int lhi  = lane >> 4, llo = lane & 15;
    const int bm   = blockIdx.x * BM;
    const int bn   = blockIdx.y * BM;
    f4_t acc[4][4] = {};
    for (int k0 = 0; k0 < K; k0 += BK) {
        __syncthreads();
        #pragma unroll
        for (int t = 0; t < 2; ++t) {
            int c   = t * 256 + tid;
            int row = c >> 2;
            int col = (c & 3) << 3;
            {
                const float* s0 = x + (size_t)(bm + row) * K + k0 + col;
                float4 f0 = *(const float4*)(s0);
                float4 f1 = *(const float4*)(s0 + 4);
                bf8_t a8;
                a8[0]=f2b(f0.x); a8[1]=f2b(f0.y); a8[2]=f2b(f0.z); a8[3]=f2b(f0.w);
                a8[4]=f2b(f1.x); a8[5]=f2b(f1.y); a8[6]=f2b(f1.z); a8[7]=f2b(f1.w);
                *(bf8_t*)(&As[row][col]) = a8;
            }
            {
                const float* s0 = W + (size_t)(bn + row) * K + k0 + col;
                float4 f0 = *(const float4*)(s0);
                float4 f1 = *(const float4*)(s0 + 4);
                bf8_t b8;
                b8[0]=f2b(f0.x); b8[1]=f2b(f0.y); b8[2]=f2b(f0.z); b8[3]=f2b(f0.w);
                b8[4]=f2b(f1.x); b8[5]=f2b(f1.y); b8[6]=f2b(f1.z); b8[7]=f2b(f1.w);
                *(bf8_t*)(&Bs[row][col]) = b8;
            }
        }
        __syncthreads();
        bf8_t af[4], bfr[4];
        #pragma unroll
        for (int i = 0; i < 4; ++i) {
            af[i]  = *(const bf8_t*)(&As[wr * 64 + i * 16 + llo][lhi * 8]);
            bfr[i] = *(const bf8_t*)(&Bs[wc * 64 + i * 16 + llo][lhi * 8]);
        }
        #pragma unroll
        for (int mi = 0; mi < 4; ++mi)
            #pragma unroll
            for (int ni = 0; ni < 4; ++ni)
                acc[mi][ni] = mfma16(af[mi], bfr[ni], acc[mi][ni]);
    }
    if (z < 2) {
        bf16* C = z ? kws : qws;
        const float sc = z ? 1.0f : SCALE2;
        #pragma unroll
        for (int mi = 0; mi < 4; ++mi)
            #pragma unroll
            for (int ni = 0; ni < 4; ++ni)
                #pragma unroll
                for (int r = 0; r < 4; ++r) {
                    int m = bm + wr * 64 + mi * 16 + lhi * 4 + r;
                    int n = bn + wc * 64 + ni * 16 + llo;
                    int b = m >> 11, s = m & (S_LEN - 1);
                    int h = n >> 6,  d = n & (DK - 1);
                    C[(((size_t)(b * NH + h) * S_LEN) + s) * DK + d] =
                        __float2bfloat16(acc[mi][ni][r] * sc);
                }
    } else {
        #pragma unroll
        for (int mi = 0; mi < 4; ++mi)
            #pragma unroll
            for (int ni = 0; ni < 4; ++ni) {
                int m0 = bm + wr * 64 + mi * 16 + lhi * 4;
                int n  = bn + wc * 64 + ni * 16 + llo;
                int b = m0 >> 11, s0 = m0 & (S_LEN - 1);
                int h = n >> 6,   d  = n & (DK - 1);
                s4_t pk;
                #pragma unroll
                for (int r = 0; r < 4; ++r) pk[r] = f2b(acc[mi][ni][r]);
                *(s4_t*)&vtws[(((size_t)(b * NH + h) * DK) + d) * S_LEN + s0] = pk;
            }
    }
}

__global__ __launch_bounds__(256)
void gemm_o_f32(const bf16* __restrict__ A, const float* __restrict__ W,
                float* __restrict__ C) {
    constexpr int N = DM;
    constexpr int K = DM;
    constexpr int BM = 128, BN = 64, BK = 32, LDT = BK + 8;
    __shared__ bf16 As[BM][LDT];
    __shared__ bf16 Bs[BN][LDT];
    const int tid  = threadIdx.x;
    const int lane = tid & 63;
    const int w    = tid >> 6;
    const int wr   = w >> 1, wc = w & 1;
    const int lhi  = lane >> 4, llo = lane & 15;
    const int bm   = blockIdx.x * BM;
    const int bn   = blockIdx.y * BN;
    f4_t acc[4][2] = {};
    for (int k0 = 0; k0 < K; k0 += BK) {
        __syncthreads();
        #pragma unroll
        for (int t = 0; t < 2; ++t) {
            int c   = t * 256 + tid;
            int row = c >> 2;
            int col = (c & 3) << 3;
            *(bf8_t*)(&As[row][col]) =
                *(const bf8_t*)(A + (size_t)(bm + row) * K + k0 + col);
        }
        {
            int row = tid >> 2;
            int col = (tid & 3) << 3;
            const float* s0 = W + (size_t)(bn + row) * K + k0 + col;
            float4 f0 = *(const float4*)(s0);
            float4 f1 = *(const float4*)(s0 + 4);
            bf8_t b8;
            b8[0]=f2b(f0.x); b8[1]=f2b(f0.y); b8[2]=f2b(f0.z); b8[3]=f2b(f0.w);
            b8[4]=f2b(f1.x); b8[5]=f2b(f1.y); b8[6]=f2b(f1.z); b8[7]=f2b(f1.w);
            *(bf8_t*)(&Bs[row][col]) = b8;
        }
        __syncthreads();
        bf8_t af[4], bfr[2];
        #pragma unroll
        for (int i = 0; i < 4; ++i)
            af[i] = *(const bf8_t*)(&As[wr * 64 + i * 16 + llo][lhi * 8]);
        #pragma unroll
        for (int i = 0; i < 2; ++i)
            bfr[i] = *(const bf8_t*)(&Bs[wc * 32 + i * 16 + llo][lhi * 8]);
        #pragma unroll
        for (int mi = 0; mi < 4; ++mi)
            #pragma unroll
            for (int ni = 0; ni < 2; ++ni)
                acc[mi][ni] = mfma16(af[mi], bfr[ni], acc[mi][ni]);
    }
    #pragma unroll
    for (int mi = 0; mi < 4; ++mi)
        #pragma unroll
        for (int ni = 0; ni < 2; ++ni)
            #pragma unroll
            for (int r = 0; r < 4; ++r) {
                int m = bm + wr * 64 + mi * 16 + lhi * 4 + r;
                int n = bn + wc * 32 + ni * 16 + llo;
                C[(size_t)m * N + n] = acc[mi][ni][r];
            }
}

// ---------------------------------------------------------------------------
// Causal flash attention (round-6, swapped QK^T) — unchanged.
// ---------------------------------------------------------------------------
__global__ __launch_bounds__(256, 3)
void attn_fwd(const bf16* __restrict__ Q, const bf16* __restrict__ K,
              const bf16* __restrict__ Vt, bf16* __restrict__ AO) {
    __shared__ bf16 Ks[2][64][72];
    __shared__ bf16 Vs[2][64][72];
    __shared__ bf16 Pl[4][16][72];

    const int bh = blockIdx.x;
    const int qt = 31 - (int)blockIdx.y;
    const int q0 = qt * 64;
    const int nt = qt + 1;

    const bf16* Qh = Q  + (size_t)bh * S_LEN * DK;
    const bf16* Kh = K  + (size_t)bh * S_LEN * DK;
    const bf16* Vh = Vt + (size_t)bh * DK * S_LEN;

    const int tid  = threadIdx.x;
    const int lane = tid & 63;
    const int w    = tid >> 6;
    const int lhi  = lane >> 4, llo = lane & 15;
    const int r0   = tid >> 3;
    const int scol = (tid & 7) << 3;

    const bf16* qrow = Qh + (size_t)(q0 + w * 16 + llo) * DK;
    const bf8_t qf0 = *(const bf8_t*)(qrow + lhi * 8);
    const bf8_t qf1 = *(const bf8_t*)(qrow + 32 + lhi * 8);

    bf8_t ones;
    #pragma unroll
    for (int j = 0; j < 8; ++j) ones[j] = (short)0x3F80;

    *(bf8_t*)&Ks[0][r0][scol]      = *(const bf8_t*)(Kh + (size_t)r0 * DK + scol);
    *(bf8_t*)&Ks[0][r0 + 32][scol] = *(const bf8_t*)(Kh + (size_t)(r0 + 32) * DK + scol);
    *(bf8_t*)&Vs[0][r0][scol]      = *(const bf8_t*)(Vh + (size_t)r0 * S_LEN + scol);
    *(bf8_t*)&Vs[0][r0 + 32][scol] = *(const bf8_t*)(Vh + (size_t)(r0 + 32) * S_LEN + scol);
    __syncthreads();

    f4_t o[4] = {};
    float lr[4] = {0.f, 0.f, 0.f, 0.f};
    float mr = NEG_BIG;

    bf8_t kr0, kr1, vr0, vr1;

    for (int t = 0; t < nt; ++t) {
        const int kv0 = t * 64;
        const int cur = t & 1;

        if (t + 1 < nt) {
            kr0 = *(const bf8_t*)(Kh + (size_t)(kv0 + 64 + r0) * DK + scol);
            kr1 = *(const bf8_t*)(Kh + (size_t)(kv0 + 96 + r0) * DK + scol);
            vr0 = *(const bf8_t*)(Vh + (size_t)r0 * S_LEN + kv0 + 64 + scol);
            vr1 = *(const bf8_t*)(Vh + (size_t)(r0 + 32) * S_LEN + kv0 + 64 + scol);
        }

        f4_t s[4] = {};
        __builtin_amdgcn_s_setprio(1);
        #pragma unroll
        for (int nf = 0; nf < 4; ++nf) {
            bf8_t k0f = *(const bf8_t*)&Ks[cur][nf * 16 + llo][lhi * 8];
            bf8_t k1f = *(const bf8_t*)&Ks[cur][nf * 16 + llo][32 + lhi * 8];
            s[nf] = mfma16(k0f, qf0, s[nf]);
            s[nf] = mfma16(k1f, qf1, s[nf]);
        }
        __builtin_amdgcn_s_setprio(0);

        if (kv0 == q0) {
            const int qloc = w * 16 + llo;
            #pragma unroll
            for (int nf = 0; nf < 4; ++nf)
                #pragma unroll
                for (int r = 0; r < 4; ++r)
                    if (nf * 16 + lhi * 4 + r > qloc) s[nf][r] = NEG_BIG;
        }

        float pm = s[0][0];
        #pragma unroll
        for (int nf = 0; nf < 4; ++nf)
            #pragma unroll
            for (int r = 0; r < 4; ++r) pm = fmaxf(pm, s[nf][r]);
        pm = fmaxf(pm, __shfl_xor(pm, 16));
        pm = fmaxf(pm, __shfl_xor(pm, 32));

        float mn = fmaxf(mr, pm);
        float alpha = exp2f(mr - mn);
        mr = mn;

        #pragma unroll
        for (int nf = 0; nf < 4; ++nf) {
            s4_t pk;
            #pragma unroll
            for (int r = 0; r < 4; ++r) pk[r] = f2b(exp2f(s[nf][r] - mr));
            *(s4_t*)&Pl[w][llo][nf * 16 + lhi * 4] = pk;
        }

        float alpha_o[4];
        #pragma unroll
        for (int r = 0; r < 4; ++r) alpha_o[r] = __shfl(alpha, lhi * 4 + r);
        #pragma unroll
        for (int df = 0; df < 4; ++df)
            #pragma unroll
            for (int r = 0; r < 4; ++r) o[df][r] *= alpha_o[r];

        asm volatile("s_waitcnt lgkmcnt(0)" ::: "memory");
        __builtin_amdgcn_sched_barrier(0);

        bf8_t pa0 = *(const bf8_t*)&Pl[w][llo][lhi * 8];
        bf8_t pa1 = *(const bf8_t*)&Pl[w][llo][32 + lhi * 8];

        f4_t rsacc = {};
        rsacc = mfma16(pa0, ones, rsacc);
        rsacc = mfma16(pa1, ones, rsacc);

        __builtin_amdgcn_s_setprio(1);
        #pragma unroll
        for (int df = 0; df < 4; ++df) {
            bf8_t vb0 = *(const bf8_t*)&Vs[cur][df * 16 + llo][lhi * 8];
            bf8_t vb1 = *(const bf8_t*)&Vs[cur][df * 16 + llo][32 + lhi * 8];
            o[df] = mfma16(pa0, vb0, o[df]);
            o[df] = mfma16(pa1, vb1, o[df]);
        }
        __builtin_amdgcn_s_setprio(0);

        #pragma unroll
        for (int r = 0; r < 4; ++r) lr[r] = lr[r] * alpha_o[r] + rsacc[r];

        if (t + 1 < nt) {
            *(bf8_t*)&Ks[cur ^ 1][r0][scol]      = kr0;
            *(bf8_t*)&Ks[cur ^ 1][r0 + 32][scol] = kr1;
            *(bf8_t*)&Vs[cur ^ 1][r0][scol]      = vr0;
            *(bf8_t*)&Vs[cur ^ 1][r0 + 32][scol] = vr1;
        }
        __syncthreads();
    }

    const int b = bh >> 4, h = bh & (NH - 1);
    #pragma unroll
    for (int r = 0; r < 4; ++r) {
        float inv = 1.0f / lr[r];
        int q = q0 + w * 16 + lhi * 4 + r;
        bf16* orow = AO + ((size_t)(b * S_LEN + q) * DM) + h * DK;
        #pragma unroll
        for (int df = 0; df < 4; ++df)
            orow[df * 16 + llo] = __float2bfloat16(o[df][r] * inv);
    }
}

// ---------------------------------------------------------------------------
extern "C" void kernel_launch(void* const* d_in, const int* in_sizes, int n_in,
                              void* d_out, int out_size, void* d_ws, size_t ws_size,
                              hipStream_t stream) {
    const float* x  = (const float*)d_in[0];
    const float* wq = (const float*)d_in[1];
    const float* wk = (const float*)d_in[2];
    const float* wv = (const float*)d_in[3];
    const float* wo = (const float*)d_in[4];
    float* out = (float*)d_out;

    const size_t SEG   = 1u << 20;
    const size_t elems = 4 * SEG;               // 4 Mi elems per activation
    const size_t need_fast = (8 * SEG + 3 * elems) * sizeof(bf16);  // 40 MB

    dim3 blk(256);

    if (ws_size >= need_fast) {
        // fast path: pre-convert + global_load_lds GEMMs
        bf16* ob   = (bf16*)d_ws;               // [xb | wqb | wkb | wvb | wob]
        bf16* xb   = ob;
        bf16* wqb  = ob + 4 * SEG;
        bf16* wkb  = ob + 5 * SEG;
        bf16* wvb  = ob + 6 * SEG;
        bf16* wob  = ob + 7 * SEG;
        bf16* qws  = ob + 8 * SEG;
        bf16* kws  = qws + elems;
        bf16* vtws = kws + elems;
        bf16* aws  = xb;                        // alias: xb dead after QKV GEMMs

        cvt_all<<<4096, blk, 0, stream>>>(x, wq, wk, wv, wo, ob);
        gemm_qkv_b<<<dim3(32, 8, 3), blk, 0, stream>>>(xb, wqb, wkb, wvb,
                                                       qws, kws, vtws);
        attn_fwd<<<dim3(NBATCH * NH, 32), blk, 0, stream>>>(qws, kws, vtws, aws);
        gemm_o_b<<<dim3(32, 8), blk, 0, stream>>>(aws, wob, out);
    } else {
        if (ws_size < elems * 4 * sizeof(bf16)) return;
        bf16* qws  = (bf16*)d_ws;
        bf16* kws  = qws + elems;
        bf16* vtws = kws + elems;
        bf16* aws  = vtws + elems;

        gemm_qkv_f32<<<dim3(32, 8, 3), blk, 0, stream>>>(x, wq, wk, wv,
                                                         qws, kws, vtws);
        attn_fwd<<<dim3(NBATCH * NH, 32), blk, 0, stream>>>(qws, kws, vtws, aws);
        gemm_o_f32<<<dim3(32, 16), blk, 0, stream>>>(aws, wo, out);
    }
}